// Round 14
// baseline (2932.685 us; speedup 1.0000x reference)
//
#include <hip/hip_runtime.h>
#include <hip/hip_bf16.h>

// Seq2Seq GRU+attention, MI355X. Round 14: dec chain 3->2 hops. A-blocks
// publish bf16 local-max partials + stats; W-blocks fuse the online-softmax
// combine into sx staging (q0-combine hop and Xf/sxb deleted). Prep kernels
// merged (1 cvt + 1 gather). Base: r13 (LDS-resident attn, FC-in-dec).

#define B_  32
#define TX_ 512
#define TY_ 127
#define E_  256
#define H_  512
#define G3_ 1536
#define V_  32000
#define NA_ 128
#define NW_ 32
#define NF_ 80

typedef unsigned short u16;
typedef short short8 __attribute__((ext_vector_type(8)));
typedef float f32x4 __attribute__((ext_vector_type(4)));
typedef float f32x2 __attribute__((ext_vector_type(2)));
typedef unsigned int u32x4 __attribute__((ext_vector_type(4)));

__device__ __forceinline__ float bfu(u16 h){ union{unsigned u; float f;} x; x.u=((unsigned)h)<<16; return x.f; }
__device__ __forceinline__ float bflo(unsigned p){ union{unsigned u; float f;} x; x.u=p<<16; return x.f; }
__device__ __forceinline__ float bfhi(unsigned p){ union{unsigned u; float f;} x; x.u=p&0xffff0000u; return x.f; }
__device__ __forceinline__ u16 f2bf(float f){ union{float f; unsigned u;} v; v.f=f; unsigned r=v.u+0x7fffu+((v.u>>16)&1u); return (u16)(r>>16); }
__device__ __forceinline__ float sigm(float x){ return 1.f/(1.f+__expf(-x)); }
__device__ __forceinline__ float tanh_f(float x){ return 1.f - 2.f/(__expf(2.f*x)+1.f); }

// ---- L2-bypass (coherent-point) accessors ----
__device__ __forceinline__ u32x4 ld16_c(const void* p){
  u32x4 r;
  asm volatile("global_load_dwordx4 %0, %1, off sc0 sc1\n\ts_waitcnt vmcnt(0)"
               : "=v"(r) : "v"(p) : "memory");
  return r;
}
__device__ __forceinline__ f32x2 ld8_c(const void* p){
  f32x2 r;
  asm volatile("global_load_dwordx2 %0, %1, off sc0 sc1\n\ts_waitcnt vmcnt(0)"
               : "=v"(r) : "v"(p) : "memory");
  return r;
}
__device__ __forceinline__ void ld4x16_c(const u16* a, const u16* b, const u16* c, const u16* d,
                                         u32x4& q0, u32x4& q1, u32x4& q2, u32x4& q3){
  asm volatile(
    "global_load_dwordx4 %0, %4, off sc0 sc1\n\t"
    "global_load_dwordx4 %1, %5, off sc0 sc1\n\t"
    "global_load_dwordx4 %2, %6, off sc0 sc1\n\t"
    "global_load_dwordx4 %3, %7, off sc0 sc1\n\t"
    "s_waitcnt vmcnt(0)"
    : "=&v"(q0),"=&v"(q1),"=&v"(q2),"=&v"(q3)
    : "v"(a),"v"(b),"v"(c),"v"(d) : "memory");
}
__device__ __forceinline__ void st_u16_c(void* p, unsigned v){
  asm volatile("global_store_short %0, %1, off sc0 sc1" :: "v"(p), "v"(v) : "memory");
}
__device__ __forceinline__ void st8_c(void* p, float a, float b){
  f32x2 v; v.x=a; v.y=b;
  asm volatile("global_store_dwordx2 %0, %1, off sc0 sc1" :: "v"(p), "v"(v) : "memory");
}

__device__ __forceinline__ void spin_rel(int* p, int tgt){
  int n = 0;
  while (__hip_atomic_load(p, __ATOMIC_RELAXED, __HIP_MEMORY_SCOPE_AGENT) < tgt){
    __builtin_amdgcn_s_sleep(1);
    if (++n > (1<<22)) break;   // bounded: bug -> wrong output, not hang
  }
}
__device__ __forceinline__ void spin_rel_slow(int* p, int tgt){
  int n = 0;
  while (__hip_atomic_load(p, __ATOMIC_RELAXED, __HIP_MEMORY_SCOPE_AGENT) < tgt){
    __builtin_amdgcn_s_sleep(16);
    if (++n > (1<<20)) break;
  }
}

// stage [32][512] bf16 (sc1-written) global -> stgl LDS via bypass loads
__device__ __forceinline__ void stage4_c(u16 (*stgl)[520], const u16* src, int tid){
  const u16* b0 = src + (size_t)(tid>>6)*H_ + (tid&63)*8;
  const u16* b1 = b0 + (size_t)8*H_;
  const u16* b2 = b0 + (size_t)16*H_;
  const u16* b3 = b0 + (size_t)24*H_;
  u32x4 q0,q1,q2,q3;
  asm volatile(
    "global_load_dwordx4 %0, %4, off sc0 sc1\n\t"
    "global_load_dwordx4 %1, %5, off sc0 sc1\n\t"
    "global_load_dwordx4 %2, %6, off sc0 sc1\n\t"
    "global_load_dwordx4 %3, %7, off sc0 sc1\n\t"
    "s_waitcnt vmcnt(0)"
    : "=&v"(q0),"=&v"(q1),"=&v"(q2),"=&v"(q3)
    : "v"(b0),"v"(b1),"v"(b2),"v"(b3) : "memory");
  int r = tid>>6, c = (tid&63)*8;
  *(u32x4*)&stgl[r][c]    = q0;
  *(u32x4*)&stgl[r+8][c]  = q1;
  *(u32x4*)&stgl[r+16][c] = q2;
  *(u32x4*)&stgl[r+24][c] = q3;
}

// ---------- merged f32->bf16 weight conversions (6 tables, 1 launch) ----------
__global__ void cvt_all(const float* __restrict__ fcW, const float* __restrict__ eWih,
                        const float* __restrict__ dWih, const float* __restrict__ eWhh,
                        const float* __restrict__ dWhh,
                        u16* __restrict__ Wfc, u16* __restrict__ eWihB, u16* __restrict__ dWihE,
                        u16* __restrict__ eWhhB, u16* __restrict__ dWhhB, u16* __restrict__ dWihS){
  int r = blockIdx.x;
  const float* s; u16* d; int cols, sld, soff;
  if      (r < V_)        {            s=fcW;  d=Wfc;   cols=H_; sld=H_;    soff=0;  }
  else if (r < V_+G3_)    { r-=V_;     s=eWih; d=eWihB; cols=E_; sld=E_;    soff=0;  }
  else if (r < V_+2*G3_)  { r-=V_+G3_; s=dWih; d=dWihE; cols=E_; sld=E_+H_; soff=0;  }
  else if (r < V_+3*G3_)  { r-=V_+2*G3_; s=eWhh; d=eWhhB; cols=H_; sld=H_;  soff=0;  }
  else if (r < V_+4*G3_)  { r-=V_+3*G3_; s=dWhh; d=dWhhB; cols=H_; sld=H_;  soff=0;  }
  else                    { r-=V_+4*G3_; s=dWih; d=dWihS; cols=H_; sld=E_+H_; soff=E_; }
  const float* sp = s + (size_t)r*sld + soff;
  u16* dp = d + (size_t)r*cols;
  for (int c = threadIdx.x; c < cols; c += blockDim.x) dp[c] = f2bf(sp[c]);
}

// ---------- merged embedding gathers (x + y) ----------
__global__ void gather_all(const float* __restrict__ emb, const int* __restrict__ x,
                           const int* __restrict__ y, u16* __restrict__ ex,
                           u16* __restrict__ embY){
  int m = blockIdx.x;
  if (m < B_*TX_){
    int id = x[m];
    ex[(size_t)m*E_ + threadIdx.x] = f2bf(emb[(size_t)id*E_ + threadIdx.x]);
  } else {
    m -= B_*TX_;
    int bb = m / TY_, tt = m - bb*TY_;
    int id = y[bb*128 + tt];
    embY[(size_t)m*E_ + threadIdx.x] = f2bf(emb[(size_t)id*E_ + threadIdx.x]);
  }
}

// ---------- bf16 MFMA GEMM (Gx/Gy precomputes) ----------
__global__ __launch_bounds__(256) void gemm_bf16(
    const u16* __restrict__ A, int lda, const u16* __restrict__ Bm, int ldb,
    void* __restrict__ Cout, int ldc, const float* __restrict__ bias,
    int M, int K, int out_bf16)
{
  int wave = threadIdx.x >> 6, lane = threadIdx.x & 63;
  int m0 = blockIdx.x*128 + (wave>>1)*64;
  int n0 = blockIdx.y*128 + (wave&1)*64;
  int lr = lane & 15, lk = (lane>>4)*8;
  f32x4 acc[4][4];
  #pragma unroll
  for (int i=0;i<4;++i)
    #pragma unroll
    for (int j=0;j<4;++j) acc[i][j] = (f32x4){0.f,0.f,0.f,0.f};
  for (int k0=0; k0<K; k0+=32){
    short8 af[4], bfv[4];
    #pragma unroll
    for (int i=0;i<4;++i){
      int row = m0 + i*16 + lr; if (row > M-1) row = M-1;
      af[i] = *(const short8*)(A + (size_t)row*lda + k0 + lk);
    }
    #pragma unroll
    for (int j=0;j<4;++j){
      int col = n0 + j*16 + lr;
      bfv[j] = *(const short8*)(Bm + (size_t)col*ldb + k0 + lk);
    }
    #pragma unroll
    for (int i=0;i<4;++i)
      #pragma unroll
      for (int j=0;j<4;++j)
        acc[i][j] = __builtin_amdgcn_mfma_f32_16x16x32_bf16(af[i], bfv[j], acc[i][j], 0,0,0);
  }
  int rbase = (lane>>4)*4;
  #pragma unroll
  for (int i=0;i<4;++i)
    #pragma unroll
    for (int r=0;r<4;++r){
      int row = m0 + i*16 + rbase + r;
      if (row < M){
        #pragma unroll
        for (int j=0;j<4;++j){
          int col = n0 + j*16 + lr;
          float v = acc[i][j][r] + bias[col];
          if (out_bf16) ((u16*)Cout)[(size_t)row*ldc + col] = f2bf(v);
          else          ((float*)Cout)[(size_t)row*ldc + col] = v;
        }
      }
    }
}

// ---------- encoder: 32 blocks x 512 thr, rotated loop (r13-proven) ----------
__global__ __launch_bounds__(512,2) void enc_v3(
    const u16* __restrict__ Gx, const u16* __restrict__ Whh_bf,
    const float* __restrict__ bhh, u16* __restrict__ eh,
    u16* __restrict__ hgd, int* flags)
{
  __shared__ __align__(16) u16 stgl[32][520];
  __shared__ __align__(16) float gH[32][52];
  int tid = threadIdx.x, g = blockIdx.x;
  int wave = tid>>6, lane = tid&63;
  int pb = tid>>4, pu = tid&15, u = g*16 + pu;

  short8 fH[16];
  int mt = wave/3, nt = wave%3;
  if (wave < 6){
    int row = nt*H_ + g*16 + (lane&15);
    int kb = (lane>>4)*8;
    #pragma unroll
    for (int ks=0;ks<16;++ks)
      fH[ks] = *(const short8*)(Whh_bf + (size_t)row*H_ + ks*32 + kb);
  }
  float bhR = bhh[u], bhZ = bhh[u+H_], bhN = bhh[u+2*H_];
  float hloc = 0.f;
  size_t gx0 = (size_t)pb*TX_*G3_;
  float iR = bfu(Gx[gx0+u]), iZ = bfu(Gx[gx0+H_+u]), iN = bfu(Gx[gx0+2*H_+u]);

  for (int t=0;t<TX_;++t){
    if (t > 0){
      if (tid < 32) spin_rel(&flags[tid], t);
      __syncthreads();
      asm volatile("" ::: "memory");
    }
    stage4_c(stgl, hgd + (size_t)(t&1)*B_*H_, tid);
    __syncthreads();
    if (wave < 6){
      f32x4 acc = (f32x4){0.f,0.f,0.f,0.f};
      int ar = mt*16 + (lane&15), ak = (lane>>4)*8;
      #pragma unroll
      for (int ks=0;ks<16;++ks)
        acc = __builtin_amdgcn_mfma_f32_16x16x32_bf16(*(const short8*)&stgl[ar][ks*32+ak], fH[ks], acc, 0,0,0);
      int dr = mt*16 + ((lane>>4)<<2), dc = nt*16 + (lane&15);
      #pragma unroll
      for (int r=0;r<4;++r) gH[dr+r][dc] = acc[r];
    }
    __syncthreads();
    float r = sigm(iR + gH[pb][pu]    + bhR);
    float z = sigm(iZ + gH[pb][16+pu] + bhZ);
    float n = tanh_f(iN + r*(gH[pb][32+pu] + bhN));
    hloc = (1.f-z)*n + z*hloc;
    u16 hb = f2bf(hloc);
    st_u16_c(&hgd[(size_t)((t+1)&1)*B_*H_ + (size_t)pb*H_ + u], (unsigned)hb);
    __syncthreads();   // drain h stores
    if (tid == 0)
      __hip_atomic_store(&flags[blockIdx.x], t+1, __ATOMIC_RELAXED, __HIP_MEMORY_SCOPE_AGENT);
    // post-arrive work, hidden inside other blocks' wait:
    eh[((size_t)pb*TX_ + t)*H_ + u] = hb;
    if (t+1 < TX_){
      size_t g2 = ((size_t)pb*TX_ + (t+1))*G3_;
      iR = bfu(Gx[g2+u]); iZ = bfu(Gx[g2+H_+u]); iN = bfu(Gx[g2+2*H_+u]);
    }
  }
}

// ---------- decoder+FC: 240 blocks x 512 thr (128 A + 32 W + 80 FC) ----------
// 2-hop chain: Hf -> A(scores+SM+PV, publish bf16 partials+stats) -> Pf ->
//              W(combine-in-staging + gS + pointwise) -> Hf.
__global__ __launch_bounds__(512,2) void dec_v6(
    const u16* __restrict__ eh, const u16* __restrict__ Gy,
    const u16* __restrict__ WihS_bf, const u16* __restrict__ Whh_bf,
    const float* __restrict__ dbhh, const float* __restrict__ hinit,
    const u16* __restrict__ Wfc_bf, const float* __restrict__ fcB,
    u16* __restrict__ part_bf, float* __restrict__ statsg,
    u16* __restrict__ hdd2, u16* __restrict__ XfcT, float* __restrict__ out,
    int* Pf, int* Hf, int* ticket)
{
  struct AS {
    u16   ehq[128][512];
    u16   oxb[512];
    float sc[128];
    float pt[8][512];
    float red[16];
  };
  struct WS {
    u16 stgl[32][520];
    float gS[32][52]; float gH[32][52];
    float stf[256];     // 128 (m,l) pairs
    float scl[32][4];   // per-batch combine scales
  };
  struct FS { u16 Ab[128][520]; int tkS; };
  __shared__ __align__(16) char smem_[sizeof(AS)];
  int tid = threadIdx.x;
  int wave = tid>>6, lane = tid&63;

  if (blockIdx.x < NA_){
    // ===== role A: attention quarter (batch b, chunk q) =====
    AS& S = *(AS*)smem_;
    int b = blockIdx.x >> 2, q = blockIdx.x & 3;
    { // preload eh quarter, swizzled (once)
      const u16* ehg = eh + ((size_t)b*TX_ + q*128)*H_;
      int row = tid>>2, c0 = (tid&3)*128;
      #pragma unroll
      for (int j=0;j<16;++j){
        int u0 = c0 + j*8;
        uint4 v = *(const uint4*)(ehg + (size_t)row*H_ + u0);
        *(uint4*)&S.ehq[row][u0 ^ ((row&7)<<3)] = v;
      }
    }
    __syncthreads();
    bool bl = (lane&15) == 0;
    for (int t=0;t<TY_;++t){
      if (t > 0){
        if (tid < NW_) spin_rel(&Hf[tid], t);
        __syncthreads();
        asm volatile("" ::: "memory");
        if (tid < 64){
          u32x4 qv = ld16_c(hdd2 + (size_t)(t&1)*B_*H_ + (size_t)b*H_ + tid*8);
          *(u32x4*)&S.oxb[tid*8] = qv;
        }
      } else {
        S.oxb[tid] = f2bf(hinit[tid]);
      }
      __syncthreads();
      { // scores
        f32x4 acS = (f32x4){0.f,0.f,0.f,0.f};
        int arow = wave*16 + (lane&15);
        int swz = (arow&7)<<3;
        #pragma unroll
        for (int kt=0;kt<16;++kt){
          short8 bf = (short8){0,0,0,0,0,0,0,0};
          if (bl) bf = *(const short8*)&S.oxb[kt*32 + (lane>>4)*8];
          short8 af_ = *(const short8*)&S.ehq[arow][(kt*32 + (lane>>4)*8) ^ swz];
          acS = __builtin_amdgcn_mfma_f32_16x16x32_bf16(af_, bf, acS, 0,0,0);
        }
        if (bl){
          #pragma unroll
          for (int r=0;r<4;++r) S.sc[wave*16 + (lane>>4)*4 + r] = acS[r];
        }
      }
      __syncthreads();
      // local stats
      float mq, lq;
      {
        float v = (tid<128) ? S.sc[tid] : -3e38f;
        #pragma unroll
        for (int o=32;o>0;o>>=1) v = fmaxf(v, __shfl_xor(v, o));
        if (lane==0) S.red[wave] = v;
        __syncthreads();
        mq = fmaxf(S.red[0], S.red[1]);
        float e = 0.f;
        if (tid<128){ e = __expf(S.sc[tid] - mq); S.sc[tid] = e; }
        float s2 = e;
        #pragma unroll
        for (int o=32;o>0;o>>=1) s2 += __shfl_xor(s2, o);
        if (lane==0) S.red[8+wave] = s2;
        __syncthreads();
        lq = S.red[8] + S.red[9];
      }
      // PV partial (local-max-referenced, unnormalized)
      int u0 = lane*8, tseg = wave;
      f32x4 aLo = (f32x4){0.f,0.f,0.f,0.f}, aHi = (f32x4){0.f,0.f,0.f,0.f};
      #pragma unroll
      for (int j=0;j<16;++j){
        int tp = tseg*16 + j;
        short8 ev = *(const short8*)&S.ehq[tp][u0 ^ ((tp&7)<<3)];
        float av = S.sc[tp];
        aLo[0] = fmaf(bfu((u16)ev[0]), av, aLo[0]);
        aLo[1] = fmaf(bfu((u16)ev[1]), av, aLo[1]);
        aLo[2] = fmaf(bfu((u16)ev[2]), av, aLo[2]);
        aLo[3] = fmaf(bfu((u16)ev[3]), av, aLo[3]);
        aHi[0] = fmaf(bfu((u16)ev[4]), av, aHi[0]);
        aHi[1] = fmaf(bfu((u16)ev[5]), av, aHi[1]);
        aHi[2] = fmaf(bfu((u16)ev[6]), av, aHi[2]);
        aHi[3] = fmaf(bfu((u16)ev[7]), av, aHi[3]);
      }
      *(f32x4*)&S.pt[tseg][u0]   = aLo;
      *(f32x4*)&S.pt[tseg][u0+4] = aHi;
      __syncthreads();
      float sv = 0.f;
      #pragma unroll
      for (int gsg=0; gsg<8; ++gsg) sv += S.pt[gsg][tid];
      // publish bf16 partial + stats (uniform, no q0 special path)
      st_u16_c(&part_bf[(size_t)(b*4+q)*512 + tid], (unsigned)f2bf(sv));
      if (tid==0) st8_c(&statsg[(size_t)(b*4+q)*2], mq, lq);
      __syncthreads();   // drain
      if (tid==0) __hip_atomic_store(&Pf[b*4+q], t+1, __ATOMIC_RELAXED, __HIP_MEMORY_SCOPE_AGENT);
    }
  } else if (blockIdx.x < NA_ + NW_){
    // ===== role W: gates for units [16g,16g+16), all 32 batches =====
    WS& S = *(WS*)smem_;
    int g = blockIdx.x - NA_;
    int pb = tid>>4, pu = tid&15, u = g*16 + pu;
    short8 fS[16], fH[16];
    int mt = wave/3, nt = wave%3;
    if (wave < 6){
      int row = nt*H_ + g*16 + (lane&15);
      int kb = (lane>>4)*8;
      #pragma unroll
      for (int ks=0;ks<16;++ks){
        fS[ks] = *(const short8*)(WihS_bf + (size_t)row*H_ + ks*32 + kb);
        fH[ks] = *(const short8*)(Whh_bf  + (size_t)row*H_ + ks*32 + kb);
      }
    }
    float bhR = dbhh[u], bhZ = dbhh[u+H_], bhN = dbhh[u+2*H_];
    float hloc = 0.f;

    for (int t=0;t<TY_;++t){
      size_t gyb = ((size_t)pb*TY_ + t)*G3_;
      float iR = bfu(Gy[gyb+u]), iZ = bfu(Gy[gyb+H_+u]), iN = bfu(Gy[gyb+2*H_+u]);
      // pre-Pf: gH from h(t-1) (overlaps A's attention phase)
      if (tid < NW_) spin_rel(&Hf[tid], t);
      __syncthreads();
      asm volatile("" ::: "memory");
      stage4_c(S.stgl, hdd2 + (size_t)(t&1)*B_*H_, tid);
      __syncthreads();
      int ar = mt*16 + (lane&15), ak = (lane>>4)*8;
      if (wave < 6){
        f32x4 acc = (f32x4){0.f,0.f,0.f,0.f};
        #pragma unroll
        for (int ks=0;ks<16;++ks)
          acc = __builtin_amdgcn_mfma_f32_16x16x32_bf16(*(const short8*)&S.stgl[ar][ks*32+ak], fH[ks], acc, 0,0,0);
        int dr = mt*16 + ((lane>>4)<<2), dc = nt*16 + (lane&15);
        #pragma unroll
        for (int r=0;r<4;++r) S.gH[dr+r][dc] = acc[r];
      }
      // wait ALL 128 partials
      if (tid < 128) spin_rel(&Pf[tid], t+1);
      __syncthreads();           // also orders gH's stgl reads before overwrite
      asm volatile("" ::: "memory");
      // stats -> per-batch combine scales
      if (tid < 128){
        f32x2 r2 = ld8_c(&statsg[(size_t)tid*2]);
        S.stf[tid*2] = r2.x; S.stf[tid*2+1] = r2.y;
      }
      __syncthreads();
      if (tid < 32){
        float m0=S.stf[(tid*4+0)*2], l0=S.stf[(tid*4+0)*2+1];
        float m1=S.stf[(tid*4+1)*2], l1=S.stf[(tid*4+1)*2+1];
        float m2=S.stf[(tid*4+2)*2], l2=S.stf[(tid*4+2)*2+1];
        float m3=S.stf[(tid*4+3)*2], l3=S.stf[(tid*4+3)*2+1];
        float gm = fmaxf(fmaxf(m0,m1), fmaxf(m2,m3));
        float e0=__expf(m0-gm), e1=__expf(m1-gm), e2=__expf(m2-gm), e3=__expf(m3-gm);
        float inv = 1.f/(l0*e0 + l1*e1 + l2*e2 + l3*e3);
        S.scl[tid][0]=e0*inv; S.scl[tid][1]=e1*inv; S.scl[tid][2]=e2*inv; S.scl[tid][3]=e3*inv;
      }
      __syncthreads();
      // combine partials -> sx (bf16) directly into stgl
      {
        int r = tid>>4, cg0 = (tid&15)*32;
        float s0=S.scl[r][0], s1=S.scl[r][1], s2=S.scl[r][2], s3=S.scl[r][3];
        #pragma unroll
        for (int cg=0; cg<4; ++cg){
          int c0 = cg0 + cg*8;
          const u16* p0 = part_bf + ((size_t)(r*4+0))*512 + c0;
          const u16* p1 = part_bf + ((size_t)(r*4+1))*512 + c0;
          const u16* p2 = part_bf + ((size_t)(r*4+2))*512 + c0;
          const u16* p3 = part_bf + ((size_t)(r*4+3))*512 + c0;
          u32x4 q0,q1,q2,q3;
          ld4x16_c(p0,p1,p2,p3,q0,q1,q2,q3);
          u32x4 pk;
          #pragma unroll
          for (int w=0;w<4;++w){
            float vlo = bflo(q0[w])*s0 + bflo(q1[w])*s1 + bflo(q2[w])*s2 + bflo(q3[w])*s3;
            float vhi = bfhi(q0[w])*s0 + bfhi(q1[w])*s1 + bfhi(q2[w])*s2 + bfhi(q3[w])*s3;
            pk[w] = (unsigned)f2bf(vlo) | ((unsigned)f2bf(vhi) << 16);
          }
          *(u32x4*)&S.stgl[r][c0] = pk;
        }
      }
      __syncthreads();
      float sxv = bfu(S.stgl[pb][u]);
      if (wave < 6){
        f32x4 acc = (f32x4){0.f,0.f,0.f,0.f};
        #pragma unroll
        for (int ks=0;ks<16;++ks)
          acc = __builtin_amdgcn_mfma_f32_16x16x32_bf16(*(const short8*)&S.stgl[ar][ks*32+ak], fS[ks], acc, 0,0,0);
        int dr = mt*16 + ((lane>>4)<<2), dc = nt*16 + (lane&15);
        #pragma unroll
        for (int r=0;r<4;++r) S.gS[dr+r][dc] = acc[r];
      }
      __syncthreads();
      { // pointwise: i_n gets gS (sx part) UNSCALED; only gH_n (+bhh_n) r-scaled
        float r = sigm(iR + S.gS[pb][pu]    + S.gH[pb][pu]    + bhR);
        float z = sigm(iZ + S.gS[pb][16+pu] + S.gH[pb][16+pu] + bhZ);
        float n = tanh_f(iN + S.gS[pb][32+pu] + r*(S.gH[pb][32+pu] + bhN));
        hloc = (1.f-z)*n + z*hloc;
        st_u16_c(&hdd2[(size_t)((t+1)&1)*B_*H_ + (size_t)pb*H_ + u], (unsigned)f2bf(hloc));
        st_u16_c(&XfcT[((size_t)t*B_ + pb)*H_ + u], (unsigned)f2bf(hloc + sxv));
      }
      __syncthreads();   // drain h + Xfc stores
      if (tid==0) __hip_atomic_store(&Hf[g], t+1, __ATOMIC_RELAXED, __HIP_MEMORY_SCOPE_AGENT);
    }
  } else {
    // ===== role FC: out = XfcT @ Wfc^T + fcB, ticket-fed by dec progress =====
    FS& S = *(FS*)smem_;
    int lr = lane & 15, lk = (lane>>4)*8;
    int m0 = (wave>>2)*64, n0w = (wave&3)*64;
    while (true){
      if (tid == 0)
        S.tkS = __hip_atomic_fetch_add(ticket, 1, __ATOMIC_RELAXED, __HIP_MEMORY_SCOPE_AGENT);
      __syncthreads();
      int tk = S.tkS;
      __syncthreads();
      if (tk >= 32*32) break;
      int tb = tk >> 5, c = tk & 31;
      int nbase = c*4;
      int nbend = (nbase+4 < 125) ? nbase+4 : 125;
      int te = 4*tb + 4; if (te > TY_) te = TY_;
      if (tid < NW_) spin_rel_slow(&Hf[tid], te);
      __syncthreads();
      asm volatile("" ::: "memory");
      { // A band: rows [tb*128, +128) of XfcT -> LDS (bypass), 16 iters = full
        const u16* src = XfcT + (size_t)tb*128*H_;
        #pragma unroll
        for (int it2=0; it2<16; ++it2){
          int el = (it2*512 + tid)*8;
          int rr = el >> 9, cc = el & 511;
          u32x4 v = ld16_c(src + (size_t)rr*H_ + cc);
          *(u32x4*)&S.Ab[rr][cc] = v;
        }
      }
      __syncthreads();
      for (int nb = nbase; nb < nbend; ++nb){
        int ncol0 = nb*256 + n0w;
        f32x4 acc[4][4];
        #pragma unroll
        for (int i=0;i<4;++i)
          #pragma unroll
          for (int j=0;j<4;++j) acc[i][j] = (f32x4){0.f,0.f,0.f,0.f};
        for (int k0=0; k0<H_; k0+=32){
          short8 af[4], bfv[4];
          #pragma unroll
          for (int i=0;i<4;++i)
            af[i] = *(const short8*)&S.Ab[m0 + i*16 + lr][k0 + lk];
          #pragma unroll
          for (int j=0;j<4;++j)
            bfv[j] = *(const short8*)(Wfc_bf + (size_t)(ncol0 + j*16 + lr)*H_ + k0 + lk);
          #pragma unroll
          for (int i=0;i<4;++i)
            #pragma unroll
            for (int j=0;j<4;++j)
              acc[i][j] = __builtin_amdgcn_mfma_f32_16x16x32_bf16(af[i], bfv[j], acc[i][j], 0,0,0);
        }
        int rbase = (lane>>4)*4;
        #pragma unroll
        for (int i=0;i<4;++i)
          #pragma unroll
          for (int r=0;r<4;++r){
            int arow = m0 + i*16 + rbase + r;
            int t2 = tb*4 + (arow>>5), b2 = arow&31;
            if (t2 < TY_){
              #pragma unroll
              for (int j=0;j<4;++j){
                int col = ncol0 + j*16 + lr;
                out[((size_t)b2*TY_ + t2)*V_ + col] = acc[i][j][r] + fcB[col];
              }
            }
          }
        __syncthreads();
      }
    }
  }
}

extern "C" void kernel_launch(void* const* d_in, const int* in_sizes, int n_in,
                              void* d_out, int out_size, void* d_ws, size_t ws_size,
                              hipStream_t stream) {
  const int*   x     = (const int*)d_in[0];
  const int*   y     = (const int*)d_in[1];
  const float* emb   = (const float*)d_in[2];
  const float* eWih  = (const float*)d_in[3];
  const float* eWhh  = (const float*)d_in[4];
  const float* eBih  = (const float*)d_in[5];
  const float* eBhh  = (const float*)d_in[6];
  const float* dWih  = (const float*)d_in[7];
  const float* dWhh  = (const float*)d_in[8];
  const float* dBih  = (const float*)d_in[9];
  const float* dBhh  = (const float*)d_in[10];
  const float* hinit = (const float*)d_in[11];
  const float* fcW   = (const float*)d_in[12];
  const float* fcB   = (const float*)d_in[13];
  float* out = (float*)d_out;
  (void)in_sizes; (void)n_in; (void)out_size; (void)ws_size;

  char* p = (char*)d_ws;
  auto take = [&](size_t bytes)->char*{ char* r = p; p += (bytes + 255) & ~(size_t)255; return r; };
  u16* Wfc_bf   = (u16*)take((size_t)V_*H_*2);
  u16* ex_bf    = (u16*)take((size_t)B_*TX_*E_*2);
  u16* eWih_bf  = (u16*)take((size_t)G3_*E_*2);
  u16* Gx_bf    = (u16*)take((size_t)B_*TX_*G3_*2);
  u16* eh_bf    = (u16*)take((size_t)B_*TX_*H_*2);
  u16* embY_bf  = (u16*)take((size_t)4096*E_*2);
  u16* dWihE_bf = (u16*)take((size_t)G3_*E_*2);
  u16* Gy_bf    = (u16*)take((size_t)4096*G3_*2);
  u16* XfcT_bf  = (u16*)take((size_t)4096*H_*2);   // t-major [128][32][512]
  u16* eWhh_bf  = (u16*)take((size_t)G3_*H_*2);
  u16* dWhh_bf  = (u16*)take((size_t)G3_*H_*2);
  u16* dWihS_bf = (u16*)take((size_t)G3_*H_*2);
  u16* hgd      = (u16*)take((size_t)2*B_*H_*2);
  u16* hdd2     = (u16*)take((size_t)2*B_*H_*2);
  u16* part_bf  = (u16*)take((size_t)NA_*H_*2);    // bf16 partials [128][512]
  float* statsg = (float*)take((size_t)NA_*2*4);
  int* flagsE   = (int*)take(256);
  int* ctrl     = (int*)take(4096);
  int* Pf = ctrl, *Hf = ctrl+160, *ticket = ctrl+200;

  hipMemsetAsync(flagsE, 0, 256, stream);
  hipMemsetAsync(ctrl, 0, 4096, stream);
  hipMemsetAsync(hgd, 0, (size_t)2*B_*H_*2, stream);
  hipMemsetAsync(hdd2, 0, (size_t)2*B_*H_*2, stream);

  cvt_all<<<dim3(V_ + 5*G3_), dim3(256), 0, stream>>>(
      fcW, eWih, dWih, eWhh, dWhh,
      Wfc_bf, eWih_bf, dWihE_bf, eWhh_bf, dWhh_bf, dWihS_bf);

  gather_all<<<dim3(B_*TX_ + B_*TY_), dim3(256), 0, stream>>>(emb, x, y, ex_bf, embY_bf);

  gemm_bf16<<<dim3(B_*TX_/128, G3_/128), dim3(256), 0, stream>>>(
      ex_bf, E_, eWih_bf, E_, Gx_bf, G3_, eBih, B_*TX_, E_, 1);
  gemm_bf16<<<dim3(32, G3_/128), dim3(256), 0, stream>>>(
      embY_bf, E_, dWihE_bf, E_, Gy_bf, G3_, dBih, B_*TY_, E_, 1);

  enc_v3<<<dim3(32), dim3(512), 0, stream>>>(Gx_bf, eWhh_bf, eBhh, eh_bf, hgd, flagsE);

  dec_v6<<<dim3(NA_+NW_+NF_), dim3(512), 0, stream>>>(
      eh_bf, Gy_bf, dWihS_bf, dWhh_bf, dBhh, hinit, Wfc_bf, fcB,
      part_bf, statsg, hdd2, XfcT_bf, out, Pf, Hf, ticket);
}

// Round 15
// 2679.211 us; speedup vs baseline: 1.0946x; 1.0946x over previous
//
#include <hip/hip_runtime.h>
#include <hip/hip_bf16.h>

// Seq2Seq GRU+attention, MI355X. Round 15: best-of composition.
// dec = r13's dec_v5 (3-hop chain; r14's 2-hop W-combine broadcast was a
// measured regression: 32 W-blocks x 128KB bypass loads/step). enc = r13's
// enc_v3. prep = r14's merged cvt_all + gather_all.

#define B_  32
#define TX_ 512
#define TY_ 127
#define E_  256
#define H_  512
#define G3_ 1536
#define V_  32000
#define NA_ 128
#define NW_ 32
#define NF_ 80

typedef unsigned short u16;
typedef short short8 __attribute__((ext_vector_type(8)));
typedef float f32x4 __attribute__((ext_vector_type(4)));
typedef float f32x2 __attribute__((ext_vector_type(2)));
typedef unsigned int u32x4 __attribute__((ext_vector_type(4)));

__device__ __forceinline__ float bfu(u16 h){ union{unsigned u; float f;} x; x.u=((unsigned)h)<<16; return x.f; }
__device__ __forceinline__ u16 f2bf(float f){ union{float f; unsigned u;} v; v.f=f; unsigned r=v.u+0x7fffu+((v.u>>16)&1u); return (u16)(r>>16); }
__device__ __forceinline__ float sigm(float x){ return 1.f/(1.f+__expf(-x)); }
__device__ __forceinline__ float tanh_f(float x){ return 1.f - 2.f/(__expf(2.f*x)+1.f); }

// ---- L2-bypass (coherent-point) accessors ----
__device__ __forceinline__ u32x4 ld16_c(const void* p){
  u32x4 r;
  asm volatile("global_load_dwordx4 %0, %1, off sc0 sc1\n\ts_waitcnt vmcnt(0)"
               : "=v"(r) : "v"(p) : "memory");
  return r;
}
__device__ __forceinline__ void st_u16_c(void* p, unsigned v){
  asm volatile("global_store_short %0, %1, off sc0 sc1" :: "v"(p), "v"(v) : "memory");
}
__device__ __forceinline__ void st8_c(void* p, float a, float b){
  f32x2 v; v.x=a; v.y=b;
  asm volatile("global_store_dwordx2 %0, %1, off sc0 sc1" :: "v"(p), "v"(v) : "memory");
}
__device__ __forceinline__ void st4f_c(void* p, float v){
  asm volatile("global_store_dword %0, %1, off sc0 sc1" :: "v"(p), "v"(v) : "memory");
}

__device__ __forceinline__ void spin_rel(int* p, int tgt){
  int n = 0;
  while (__hip_atomic_load(p, __ATOMIC_RELAXED, __HIP_MEMORY_SCOPE_AGENT) < tgt){
    __builtin_amdgcn_s_sleep(1);
    if (++n > (1<<22)) break;   // bounded: bug -> wrong output, not hang
  }
}
__device__ __forceinline__ void spin_rel_slow(int* p, int tgt){
  int n = 0;
  while (__hip_atomic_load(p, __ATOMIC_RELAXED, __HIP_MEMORY_SCOPE_AGENT) < tgt){
    __builtin_amdgcn_s_sleep(16);
    if (++n > (1<<20)) break;
  }
}

// stage [32][512] bf16 (sc1-written) global -> stgl LDS via bypass loads
__device__ __forceinline__ void stage4_c(u16 (*stgl)[520], const u16* src, int tid){
  const u16* b0 = src + (size_t)(tid>>6)*H_ + (tid&63)*8;
  const u16* b1 = b0 + (size_t)8*H_;
  const u16* b2 = b0 + (size_t)16*H_;
  const u16* b3 = b0 + (size_t)24*H_;
  u32x4 q0,q1,q2,q3;
  asm volatile(
    "global_load_dwordx4 %0, %4, off sc0 sc1\n\t"
    "global_load_dwordx4 %1, %5, off sc0 sc1\n\t"
    "global_load_dwordx4 %2, %6, off sc0 sc1\n\t"
    "global_load_dwordx4 %3, %7, off sc0 sc1\n\t"
    "s_waitcnt vmcnt(0)"
    : "=&v"(q0),"=&v"(q1),"=&v"(q2),"=&v"(q3)
    : "v"(b0),"v"(b1),"v"(b2),"v"(b3) : "memory");
  int r = tid>>6, c = (tid&63)*8;
  *(u32x4*)&stgl[r][c]    = q0;
  *(u32x4*)&stgl[r+8][c]  = q1;
  *(u32x4*)&stgl[r+16][c] = q2;
  *(u32x4*)&stgl[r+24][c] = q3;
}

// ---------- merged f32->bf16 weight conversions (6 tables, 1 launch) ----------
__global__ void cvt_all(const float* __restrict__ fcW, const float* __restrict__ eWih,
                        const float* __restrict__ dWih, const float* __restrict__ eWhh,
                        const float* __restrict__ dWhh,
                        u16* __restrict__ Wfc, u16* __restrict__ eWihB, u16* __restrict__ dWihE,
                        u16* __restrict__ eWhhB, u16* __restrict__ dWhhB, u16* __restrict__ dWihS){
  int r = blockIdx.x;
  const float* s; u16* d; int cols, sld, soff;
  if      (r < V_)        {            s=fcW;  d=Wfc;   cols=H_; sld=H_;    soff=0;  }
  else if (r < V_+G3_)    { r-=V_;     s=eWih; d=eWihB; cols=E_; sld=E_;    soff=0;  }
  else if (r < V_+2*G3_)  { r-=V_+G3_; s=dWih; d=dWihE; cols=E_; sld=E_+H_; soff=0;  }
  else if (r < V_+3*G3_)  { r-=V_+2*G3_; s=eWhh; d=eWhhB; cols=H_; sld=H_;  soff=0;  }
  else if (r < V_+4*G3_)  { r-=V_+3*G3_; s=dWhh; d=dWhhB; cols=H_; sld=H_;  soff=0;  }
  else                    { r-=V_+4*G3_; s=dWih; d=dWihS; cols=H_; sld=E_+H_; soff=E_; }
  const float* sp = s + (size_t)r*sld + soff;
  u16* dp = d + (size_t)r*cols;
  for (int c = threadIdx.x; c < cols; c += blockDim.x) dp[c] = f2bf(sp[c]);
}

// ---------- merged embedding gathers (x + y) ----------
__global__ void gather_all(const float* __restrict__ emb, const int* __restrict__ x,
                           const int* __restrict__ y, u16* __restrict__ ex,
                           u16* __restrict__ embY){
  int m = blockIdx.x;
  if (m < B_*TX_){
    int id = x[m];
    ex[(size_t)m*E_ + threadIdx.x] = f2bf(emb[(size_t)id*E_ + threadIdx.x]);
  } else {
    m -= B_*TX_;
    int bb = m / TY_, tt = m - bb*TY_;
    int id = y[bb*128 + tt];
    embY[(size_t)m*E_ + threadIdx.x] = f2bf(emb[(size_t)id*E_ + threadIdx.x]);
  }
}

// ---------- bf16 MFMA GEMM (Gx/Gy precomputes) ----------
__global__ __launch_bounds__(256) void gemm_bf16(
    const u16* __restrict__ A, int lda, const u16* __restrict__ Bm, int ldb,
    void* __restrict__ Cout, int ldc, const float* __restrict__ bias,
    int M, int K, int out_bf16)
{
  int wave = threadIdx.x >> 6, lane = threadIdx.x & 63;
  int m0 = blockIdx.x*128 + (wave>>1)*64;
  int n0 = blockIdx.y*128 + (wave&1)*64;
  int lr = lane & 15, lk = (lane>>4)*8;
  f32x4 acc[4][4];
  #pragma unroll
  for (int i=0;i<4;++i)
    #pragma unroll
    for (int j=0;j<4;++j) acc[i][j] = (f32x4){0.f,0.f,0.f,0.f};
  for (int k0=0; k0<K; k0+=32){
    short8 af[4], bfv[4];
    #pragma unroll
    for (int i=0;i<4;++i){
      int row = m0 + i*16 + lr; if (row > M-1) row = M-1;
      af[i] = *(const short8*)(A + (size_t)row*lda + k0 + lk);
    }
    #pragma unroll
    for (int j=0;j<4;++j){
      int col = n0 + j*16 + lr;
      bfv[j] = *(const short8*)(Bm + (size_t)col*ldb + k0 + lk);
    }
    #pragma unroll
    for (int i=0;i<4;++i)
      #pragma unroll
      for (int j=0;j<4;++j)
        acc[i][j] = __builtin_amdgcn_mfma_f32_16x16x32_bf16(af[i], bfv[j], acc[i][j], 0,0,0);
  }
  int rbase = (lane>>4)*4;
  #pragma unroll
  for (int i=0;i<4;++i)
    #pragma unroll
    for (int r=0;r<4;++r){
      int row = m0 + i*16 + rbase + r;
      if (row < M){
        #pragma unroll
        for (int j=0;j<4;++j){
          int col = n0 + j*16 + lr;
          float v = acc[i][j][r] + bias[col];
          if (out_bf16) ((u16*)Cout)[(size_t)row*ldc + col] = f2bf(v);
          else          ((float*)Cout)[(size_t)row*ldc + col] = v;
        }
      }
    }
}

// ---------- encoder: 32 blocks x 512 thr, rotated loop (r13-proven) ----------
__global__ __launch_bounds__(512,2) void enc_v3(
    const u16* __restrict__ Gx, const u16* __restrict__ Whh_bf,
    const float* __restrict__ bhh, u16* __restrict__ eh,
    u16* __restrict__ hgd, int* flags)
{
  __shared__ __align__(16) u16 stgl[32][520];
  __shared__ __align__(16) float gH[32][52];
  int tid = threadIdx.x, g = blockIdx.x;
  int wave = tid>>6, lane = tid&63;
  int pb = tid>>4, pu = tid&15, u = g*16 + pu;

  short8 fH[16];
  int mt = wave/3, nt = wave%3;
  if (wave < 6){
    int row = nt*H_ + g*16 + (lane&15);
    int kb = (lane>>4)*8;
    #pragma unroll
    for (int ks=0;ks<16;++ks)
      fH[ks] = *(const short8*)(Whh_bf + (size_t)row*H_ + ks*32 + kb);
  }
  float bhR = bhh[u], bhZ = bhh[u+H_], bhN = bhh[u+2*H_];
  float hloc = 0.f;
  size_t gx0 = (size_t)pb*TX_*G3_;
  float iR = bfu(Gx[gx0+u]), iZ = bfu(Gx[gx0+H_+u]), iN = bfu(Gx[gx0+2*H_+u]);

  for (int t=0;t<TX_;++t){
    if (t > 0){
      if (tid < 32) spin_rel(&flags[tid], t);
      __syncthreads();
      asm volatile("" ::: "memory");
    }
    stage4_c(stgl, hgd + (size_t)(t&1)*B_*H_, tid);
    __syncthreads();
    if (wave < 6){
      f32x4 acc = (f32x4){0.f,0.f,0.f,0.f};
      int ar = mt*16 + (lane&15), ak = (lane>>4)*8;
      #pragma unroll
      for (int ks=0;ks<16;++ks)
        acc = __builtin_amdgcn_mfma_f32_16x16x32_bf16(*(const short8*)&stgl[ar][ks*32+ak], fH[ks], acc, 0,0,0);
      int dr = mt*16 + ((lane>>4)<<2), dc = nt*16 + (lane&15);
      #pragma unroll
      for (int r=0;r<4;++r) gH[dr+r][dc] = acc[r];
    }
    __syncthreads();
    float r = sigm(iR + gH[pb][pu]    + bhR);
    float z = sigm(iZ + gH[pb][16+pu] + bhZ);
    float n = tanh_f(iN + r*(gH[pb][32+pu] + bhN));
    hloc = (1.f-z)*n + z*hloc;
    u16 hb = f2bf(hloc);
    st_u16_c(&hgd[(size_t)((t+1)&1)*B_*H_ + (size_t)pb*H_ + u], (unsigned)hb);
    __syncthreads();   // drain h stores
    if (tid == 0)
      __hip_atomic_store(&flags[blockIdx.x], t+1, __ATOMIC_RELAXED, __HIP_MEMORY_SCOPE_AGENT);
    // post-arrive work, hidden inside other blocks' wait:
    eh[((size_t)pb*TX_ + t)*H_ + u] = hb;
    if (t+1 < TX_){
      size_t g2 = ((size_t)pb*TX_ + (t+1))*G3_;
      iR = bfu(Gx[g2+u]); iZ = bfu(Gx[g2+H_+u]); iN = bfu(Gx[g2+2*H_+u]);
    }
  }
}

// ---------- decoder+FC: 240 blocks x 512 thr (128 A + 32 W + 80 FC) ----------
__global__ __launch_bounds__(512,2) void dec_v5(
    const u16* __restrict__ eh, const u16* __restrict__ Gy,
    const u16* __restrict__ WihS_bf, const u16* __restrict__ Whh_bf,
    const float* __restrict__ dbhh, const float* __restrict__ hinit,
    const u16* __restrict__ Wfc_bf, const float* __restrict__ fcB,
    u16* __restrict__ sxb, u16* __restrict__ hdd2,
    float* __restrict__ part, float* __restrict__ statsg,
    u16* __restrict__ XfcT, float* __restrict__ out,
    int* Pf, int* Xf, int* Hf, int* ticket)
{
  struct AS {
    u16   ehq[128][512];
    u16   oxb[512];
    float sc[128];
    float pt[8][512];
    float red[16];
  };
  struct WS { u16 stgl[32][520]; float gS[32][52]; float gH[32][52]; };
  struct FS { u16 Ab[128][520]; int tkS; };
  __shared__ __align__(16) char smem_[sizeof(AS)];
  int tid = threadIdx.x;
  int wave = tid>>6, lane = tid&63;

  if (blockIdx.x < NA_){
    // ===== role A: attention quarter (batch b, chunk q) =====
    AS& S = *(AS*)smem_;
    int b = blockIdx.x >> 2, q = blockIdx.x & 3;
    { // preload eh quarter, swizzled (once)
      const u16* ehg = eh + ((size_t)b*TX_ + q*128)*H_;
      int row = tid>>2, c0 = (tid&3)*128;
      #pragma unroll
      for (int j=0;j<16;++j){
        int u0 = c0 + j*8;
        uint4 v = *(const uint4*)(ehg + (size_t)row*H_ + u0);
        *(uint4*)&S.ehq[row][u0 ^ ((row&7)<<3)] = v;
      }
    }
    __syncthreads();
    bool bl = (lane&15) == 0;
    for (int t=0;t<TY_;++t){
      if (t > 0){
        if (tid < NW_) spin_rel(&Hf[tid], t);
        __syncthreads();
        asm volatile("" ::: "memory");
        if (tid < 64){
          u32x4 qv = ld16_c(hdd2 + (size_t)(t&1)*B_*H_ + (size_t)b*H_ + tid*8);
          *(u32x4*)&S.oxb[tid*8] = qv;
        }
      } else {
        S.oxb[tid] = f2bf(hinit[tid]);
      }
      __syncthreads();
      { // scores
        f32x4 acS = (f32x4){0.f,0.f,0.f,0.f};
        int arow = wave*16 + (lane&15);
        int swz = (arow&7)<<3;
        #pragma unroll
        for (int kt=0;kt<16;++kt){
          short8 bf = (short8){0,0,0,0,0,0,0,0};
          if (bl) bf = *(const short8*)&S.oxb[kt*32 + (lane>>4)*8];
          short8 af_ = *(const short8*)&S.ehq[arow][(kt*32 + (lane>>4)*8) ^ swz];
          acS = __builtin_amdgcn_mfma_f32_16x16x32_bf16(af_, bf, acS, 0,0,0);
        }
        if (bl){
          #pragma unroll
          for (int r=0;r<4;++r) S.sc[wave*16 + (lane>>4)*4 + r] = acS[r];
        }
      }
      __syncthreads();
      // local stats
      float mq, lq;
      {
        float v = (tid<128) ? S.sc[tid] : -3e38f;
        #pragma unroll
        for (int o=32;o>0;o>>=1) v = fmaxf(v, __shfl_xor(v, o));
        if (lane==0) S.red[wave] = v;
        __syncthreads();
        mq = fmaxf(S.red[0], S.red[1]);
        float e = 0.f;
        if (tid<128){ e = __expf(S.sc[tid] - mq); S.sc[tid] = e; }
        float s2 = e;
        #pragma unroll
        for (int o=32;o>0;o>>=1) s2 += __shfl_xor(s2, o);
        if (lane==0) S.red[8+wave] = s2;
        __syncthreads();
        lq = S.red[8] + S.red[9];
      }
      // PV partial (local-max-referenced, unnormalized)
      int u0 = lane*8, tseg = wave;
      f32x4 aLo = (f32x4){0.f,0.f,0.f,0.f}, aHi = (f32x4){0.f,0.f,0.f,0.f};
      #pragma unroll
      for (int j=0;j<16;++j){
        int tp = tseg*16 + j;
        short8 ev = *(const short8*)&S.ehq[tp][u0 ^ ((tp&7)<<3)];
        float av = S.sc[tp];
        aLo[0] = fmaf(bfu((u16)ev[0]), av, aLo[0]);
        aLo[1] = fmaf(bfu((u16)ev[1]), av, aLo[1]);
        aLo[2] = fmaf(bfu((u16)ev[2]), av, aLo[2]);
        aLo[3] = fmaf(bfu((u16)ev[3]), av, aLo[3]);
        aHi[0] = fmaf(bfu((u16)ev[4]), av, aHi[0]);
        aHi[1] = fmaf(bfu((u16)ev[5]), av, aHi[1]);
        aHi[2] = fmaf(bfu((u16)ev[6]), av, aHi[2]);
        aHi[3] = fmaf(bfu((u16)ev[7]), av, aHi[3]);
      }
      *(f32x4*)&S.pt[tseg][u0]   = aLo;
      *(f32x4*)&S.pt[tseg][u0+4] = aHi;
      __syncthreads();
      float sv = 0.f;
      #pragma unroll
      for (int gsg=0; gsg<8; ++gsg) sv += S.pt[gsg][tid];
      if (q != 0){
        st4f_c(&part[(size_t)(b*4+q)*512 + tid], sv);
        if (tid==0) st8_c(&statsg[(size_t)(b*4+q)*2], mq, lq);
        __syncthreads();
        if (tid==0) __hip_atomic_store(&Pf[b*4+q], t+1, __ATOMIC_RELAXED, __HIP_MEMORY_SCOPE_AGENT);
      } else {
        if (tid < 3) spin_rel(&Pf[b*4+1+tid], t+1);
        __syncthreads();
        asm volatile("" ::: "memory");
        // one burst: 3 partials + 3 stat pairs, single vmcnt
        float p1,p2,p3; f32x2 s1,s2,s3;
        {
          const float* pp1 = &part[(size_t)(b*4+1)*512 + tid];
          const float* pp2 = &part[(size_t)(b*4+2)*512 + tid];
          const float* pp3 = &part[(size_t)(b*4+3)*512 + tid];
          const float* ps1 = &statsg[(size_t)(b*4+1)*2];
          const float* ps2 = &statsg[(size_t)(b*4+2)*2];
          const float* ps3 = &statsg[(size_t)(b*4+3)*2];
          asm volatile(
            "global_load_dword %0, %6, off sc0 sc1\n\t"
            "global_load_dword %1, %7, off sc0 sc1\n\t"
            "global_load_dword %2, %8, off sc0 sc1\n\t"
            "global_load_dwordx2 %3, %9, off sc0 sc1\n\t"
            "global_load_dwordx2 %4, %10, off sc0 sc1\n\t"
            "global_load_dwordx2 %5, %11, off sc0 sc1\n\t"
            "s_waitcnt vmcnt(0)"
            : "=&v"(p1),"=&v"(p2),"=&v"(p3),"=&v"(s1),"=&v"(s2),"=&v"(s3)
            : "v"(pp1),"v"(pp2),"v"(pp3),"v"(ps1),"v"(ps2),"v"(ps3) : "memory");
        }
        float gmax = fmaxf(fmaxf(mq,s1.x), fmaxf(s2.x,s3.x));
        float e0=__expf(mq-gmax), e1=__expf(s1.x-gmax), e2=__expf(s2.x-gmax), e3=__expf(s3.x-gmax);
        float inv = 1.f/(lq*e0 + s1.y*e1 + s2.y*e2 + s3.y*e3);
        float sx = (sv*e0 + p1*e1 + p2*e2 + p3*e3) * inv;
        st_u16_c(&sxb[(size_t)b*H_ + tid], (unsigned)f2bf(sx));
        __syncthreads();
        if (tid==0) __hip_atomic_store(&Xf[b], t+1, __ATOMIC_RELAXED, __HIP_MEMORY_SCOPE_AGENT);
      }
    }
  } else if (blockIdx.x < NA_ + NW_){
    // ===== role W: gates for units [16g,16g+16), all 32 batches =====
    WS& S = *(WS*)smem_;
    int g = blockIdx.x - NA_;
    int pb = tid>>4, pu = tid&15, u = g*16 + pu;
    short8 fS[16], fH[16];
    int mt = wave/3, nt = wave%3;
    if (wave < 6){
      int row = nt*H_ + g*16 + (lane&15);
      int kb = (lane>>4)*8;
      #pragma unroll
      for (int ks=0;ks<16;++ks){
        fS[ks] = *(const short8*)(WihS_bf + (size_t)row*H_ + ks*32 + kb);
        fH[ks] = *(const short8*)(Whh_bf  + (size_t)row*H_ + ks*32 + kb);
      }
    }
    float bhR = dbhh[u], bhZ = dbhh[u+H_], bhN = dbhh[u+2*H_];
    float hloc = 0.f;

    for (int t=0;t<TY_;++t){
      size_t gyb = ((size_t)pb*TY_ + t)*G3_;
      float iR = bfu(Gy[gyb+u]), iZ = bfu(Gy[gyb+H_+u]), iN = bfu(Gy[gyb+2*H_+u]);
      // pre-Xf: gH from h(t-1)
      if (tid < NW_) spin_rel(&Hf[tid], t);
      __syncthreads();
      asm volatile("" ::: "memory");
      stage4_c(S.stgl, hdd2 + (size_t)(t&1)*B_*H_, tid);
      __syncthreads();
      int ar = mt*16 + (lane&15), ak = (lane>>4)*8;
      if (wave < 6){
        f32x4 acc = (f32x4){0.f,0.f,0.f,0.f};
        #pragma unroll
        for (int ks=0;ks<16;++ks)
          acc = __builtin_amdgcn_mfma_f32_16x16x32_bf16(*(const short8*)&S.stgl[ar][ks*32+ak], fH[ks], acc, 0,0,0);
        int dr = mt*16 + ((lane>>4)<<2), dc = nt*16 + (lane&15);
        #pragma unroll
        for (int r=0;r<4;++r) S.gH[dr+r][dc] = acc[r];
      }
      // wait sx, then gS
      if (tid < 32) spin_rel(&Xf[tid], t+1);
      __syncthreads();
      asm volatile("" ::: "memory");
      stage4_c(S.stgl, sxb, tid);
      __syncthreads();
      float sxv = bfu(S.stgl[pb][u]);
      if (wave < 6){
        f32x4 acc = (f32x4){0.f,0.f,0.f,0.f};
        #pragma unroll
        for (int ks=0;ks<16;++ks)
          acc = __builtin_amdgcn_mfma_f32_16x16x32_bf16(*(const short8*)&S.stgl[ar][ks*32+ak], fS[ks], acc, 0,0,0);
        int dr = mt*16 + ((lane>>4)<<2), dc = nt*16 + (lane&15);
        #pragma unroll
        for (int r=0;r<4;++r) S.gS[dr+r][dc] = acc[r];
      }
      __syncthreads();
      {
        float r = sigm(iR + S.gS[pb][pu]    + S.gH[pb][pu]    + bhR);
        float z = sigm(iZ + S.gS[pb][16+pu] + S.gH[pb][16+pu] + bhZ);
        float n = tanh_f(iN + S.gS[pb][32+pu] + r*(S.gH[pb][32+pu] + bhN));
        hloc = (1.f-z)*n + z*hloc;
        st_u16_c(&hdd2[(size_t)((t+1)&1)*B_*H_ + (size_t)pb*H_ + u], (unsigned)f2bf(hloc));
        st_u16_c(&XfcT[((size_t)t*B_ + pb)*H_ + u], (unsigned)f2bf(hloc + sxv));
      }
      __syncthreads();   // drain h + Xfc stores
      if (tid==0) __hip_atomic_store(&Hf[g], t+1, __ATOMIC_RELAXED, __HIP_MEMORY_SCOPE_AGENT);
    }
  } else {
    // ===== role FC: out = XfcT @ Wfc^T + fcB, ticket-fed by dec progress =====
    FS& S = *(FS*)smem_;
    int lr = lane & 15, lk = (lane>>4)*8;
    int m0 = (wave>>2)*64, n0w = (wave&3)*64;
    while (true){
      if (tid == 0)
        S.tkS = __hip_atomic_fetch_add(ticket, 1, __ATOMIC_RELAXED, __HIP_MEMORY_SCOPE_AGENT);
      __syncthreads();
      int tk = S.tkS;
      __syncthreads();
      if (tk >= 32*32) break;
      int tb = tk >> 5, c = tk & 31;
      int nbase = c*4;
      int nbend = (nbase+4 < 125) ? nbase+4 : 125;
      int te = 4*tb + 4; if (te > TY_) te = TY_;
      if (tid < NW_) spin_rel_slow(&Hf[tid], te);
      __syncthreads();
      asm volatile("" ::: "memory");
      { // A band: rows [tb*128, +128) of XfcT -> LDS (bypass), 16 iters = full
        const u16* src = XfcT + (size_t)tb*128*H_;
        #pragma unroll
        for (int it2=0; it2<16; ++it2){
          int el = (it2*512 + tid)*8;
          int rr = el >> 9, cc = el & 511;
          u32x4 v = ld16_c(src + (size_t)rr*H_ + cc);
          *(u32x4*)&S.Ab[rr][cc] = v;
        }
      }
      __syncthreads();
      for (int nb = nbase; nb < nbend; ++nb){
        int ncol0 = nb*256 + n0w;
        f32x4 acc[4][4];
        #pragma unroll
        for (int i=0;i<4;++i)
          #pragma unroll
          for (int j=0;j<4;++j) acc[i][j] = (f32x4){0.f,0.f,0.f,0.f};
        for (int k0=0; k0<H_; k0+=32){
          short8 af[4], bfv[4];
          #pragma unroll
          for (int i=0;i<4;++i)
            af[i] = *(const short8*)&S.Ab[m0 + i*16 + lr][k0 + lk];
          #pragma unroll
          for (int j=0;j<4;++j)
            bfv[j] = *(const short8*)(Wfc_bf + (size_t)(ncol0 + j*16 + lr)*H_ + k0 + lk);
          #pragma unroll
          for (int i=0;i<4;++i)
            #pragma unroll
            for (int j=0;j<4;++j)
              acc[i][j] = __builtin_amdgcn_mfma_f32_16x16x32_bf16(af[i], bfv[j], acc[i][j], 0,0,0);
        }
        int rbase = (lane>>4)*4;
        #pragma unroll
        for (int i=0;i<4;++i)
          #pragma unroll
          for (int r=0;r<4;++r){
            int arow = m0 + i*16 + rbase + r;
            int t2 = tb*4 + (arow>>5), b2 = arow&31;
            if (t2 < TY_){
              #pragma unroll
              for (int j=0;j<4;++j){
                int col = ncol0 + j*16 + lr;
                out[((size_t)b2*TY_ + t2)*V_ + col] = acc[i][j][r] + fcB[col];
              }
            }
          }
        __syncthreads();
      }
    }
  }
}

extern "C" void kernel_launch(void* const* d_in, const int* in_sizes, int n_in,
                              void* d_out, int out_size, void* d_ws, size_t ws_size,
                              hipStream_t stream) {
  const int*   x     = (const int*)d_in[0];
  const int*   y     = (const int*)d_in[1];
  const float* emb   = (const float*)d_in[2];
  const float* eWih  = (const float*)d_in[3];
  const float* eWhh  = (const float*)d_in[4];
  const float* eBih  = (const float*)d_in[5];
  const float* eBhh  = (const float*)d_in[6];
  const float* dWih  = (const float*)d_in[7];
  const float* dWhh  = (const float*)d_in[8];
  const float* dBih  = (const float*)d_in[9];
  const float* dBhh  = (const float*)d_in[10];
  const float* hinit = (const float*)d_in[11];
  const float* fcW   = (const float*)d_in[12];
  const float* fcB   = (const float*)d_in[13];
  float* out = (float*)d_out;
  (void)in_sizes; (void)n_in; (void)out_size; (void)ws_size;

  char* p = (char*)d_ws;
  auto take = [&](size_t bytes)->char*{ char* r = p; p += (bytes + 255) & ~(size_t)255; return r; };
  u16* Wfc_bf   = (u16*)take((size_t)V_*H_*2);
  u16* ex_bf    = (u16*)take((size_t)B_*TX_*E_*2);
  u16* eWih_bf  = (u16*)take((size_t)G3_*E_*2);
  u16* Gx_bf    = (u16*)take((size_t)B_*TX_*G3_*2);
  u16* eh_bf    = (u16*)take((size_t)B_*TX_*H_*2);
  u16* embY_bf  = (u16*)take((size_t)4096*E_*2);
  u16* dWihE_bf = (u16*)take((size_t)G3_*E_*2);
  u16* Gy_bf    = (u16*)take((size_t)4096*G3_*2);
  u16* XfcT_bf  = (u16*)take((size_t)4096*H_*2);   // t-major [128][32][512]
  u16* eWhh_bf  = (u16*)take((size_t)G3_*H_*2);
  u16* dWhh_bf  = (u16*)take((size_t)G3_*H_*2);
  u16* dWihS_bf = (u16*)take((size_t)G3_*H_*2);
  u16* hgd      = (u16*)take((size_t)2*B_*H_*2);
  u16* hdd2     = (u16*)take((size_t)2*B_*H_*2);
  u16* sxb      = (u16*)take((size_t)B_*H_*2);
  float* part   = (float*)take((size_t)NA_*H_*4);
  float* statsg = (float*)take((size_t)NA_*2*4);
  int* flagsE   = (int*)take(256);
  int* ctrl     = (int*)take(4096);
  int* Pf = ctrl, *Xf = ctrl+128, *Hf = ctrl+160, *ticket = ctrl+200;

  hipMemsetAsync(flagsE, 0, 256, stream);
  hipMemsetAsync(ctrl, 0, 4096, stream);
  hipMemsetAsync(hgd, 0, (size_t)2*B_*H_*2, stream);
  hipMemsetAsync(hdd2, 0, (size_t)2*B_*H_*2, stream);

  cvt_all<<<dim3(V_ + 5*G3_), dim3(256), 0, stream>>>(
      fcW, eWih, dWih, eWhh, dWhh,
      Wfc_bf, eWih_bf, dWihE_bf, eWhh_bf, dWhh_bf, dWihS_bf);

  gather_all<<<dim3(B_*TX_ + B_*TY_), dim3(256), 0, stream>>>(emb, x, y, ex_bf, embY_bf);

  gemm_bf16<<<dim3(B_*TX_/128, G3_/128), dim3(256), 0, stream>>>(
      ex_bf, E_, eWih_bf, E_, Gx_bf, G3_, eBih, B_*TX_, E_, 1);
  gemm_bf16<<<dim3(32, G3_/128), dim3(256), 0, stream>>>(
      embY_bf, E_, dWihE_bf, E_, Gy_bf, G3_, dBih, B_*TY_, E_, 1);

  enc_v3<<<dim3(32), dim3(512), 0, stream>>>(Gx_bf, eWhh_bf, eBhh, eh_bf, hgd, flagsE);

  dec_v5<<<dim3(NA_+NW_+NF_), dim3(512), 0, stream>>>(
      eh_bf, Gy_bf, dWihS_bf, dWhh_bf, dBhh, hinit, Wfc_bf, fcB,
      sxb, hdd2, part, statsg, XfcT_bf, out, Pf, Xf, Hf, ticket);
}